// Round 9
// baseline (212.942 us; speedup 1.0000x reference)
//
#include <hip/hip_runtime.h>
#include <hip/hip_bf16.h>
#include <math.h>

// Problem constants (from reference setup_inputs)
#define BATCH 8
#define SEQ   1536
#define DIM   1024
#define SEQ2  (2*SEQ)          // 3072
#define TEMP_INV 20.0f         // 1 / 0.05
// feats stored as fp8 e4m3 pre-scaled by 8 => sim accumulator carries 64x
#define EXP_SCALE (TEMP_INV / 64.0f)   // 0.3125

// GEMM tiling: 64x64 tiles, ONE WAVE per block, zero barriers, 9 blocks/CU
#define BM 64
#define BN 64
#define BK 128                          // fp8 elements per K-tile (128 B/row)
#define KITERS (DIM/BK)                 // 8
#define TILES  (SEQ2 / BM)              // 48
#define NPAIRS (TILES * (TILES+1) / 2)  // 1176 upper-triangular tile pairs

typedef int   i32x4 __attribute__((ext_vector_type(4)));
typedef int   i32x8 __attribute__((ext_vector_type(8)));
typedef float f32x4 __attribute__((ext_vector_type(4)));

#define GLOBAL_AS __attribute__((address_space(1)))
#define LDS_AS    __attribute__((address_space(3)))

__device__ inline void async_ld16(const void* g, void* lds_uniform) {
    // gfx950: direct global->LDS, 16B/lane; LDS dest = wave-uniform base + lane*16
    __builtin_amdgcn_global_load_lds((const GLOBAL_AS void*)g, (LDS_AS void*)lds_uniform, 16, 0, 0);
}

__device__ inline float wave_red64(float v) {
    #pragma unroll
    for (int m = 32; m > 0; m >>= 1) v += __shfl_xor(v, m, 64);
    return v;
}

// ---------------------------------------------------------------------------
// Kernel 1: L2-normalize both views -> fp8 e4m3 feats (x8 pre-scale)
// (R4-measured-best form: coalesced 16B/lane loads, per-dword stores.)
// ---------------------------------------------------------------------------
__global__ __launch_bounds__(256) void normalize_kernel(
        const float* __restrict__ h1, const float* __restrict__ h2,
        unsigned char* __restrict__ feats, float* __restrict__ pos_cos,
        float* __restrict__ Ng, float* __restrict__ out) {
    int w = threadIdx.x >> 6, lane = threadIdx.x & 63;
    int tok = blockIdx.x * 4 + w;                 // 0 .. B*S-1
    int b = tok / SEQ, s = tok - b * SEQ;

    const float4* a4 = (const float4*)(h1 + (size_t)tok * DIM);
    const float4* b4 = (const float4*)(h2 + (size_t)tok * DIM);
    float4 av[4], bv[4];
    #pragma unroll
    for (int it = 0; it < 4; it++) { av[it] = a4[lane + 64*it]; bv[it] = b4[lane + 64*it]; }

    float ss1 = 0.f, ss2 = 0.f, sd = 0.f;
    #pragma unroll
    for (int it = 0; it < 4; it++) {
        ss1 += av[it].x*av[it].x + av[it].y*av[it].y + av[it].z*av[it].z + av[it].w*av[it].w;
        ss2 += bv[it].x*bv[it].x + bv[it].y*bv[it].y + bv[it].z*bv[it].z + bv[it].w*bv[it].w;
        sd  += av[it].x*bv[it].x + av[it].y*bv[it].y + av[it].z*bv[it].z + av[it].w*bv[it].w;
    }
    ss1 = wave_red64(ss1); ss2 = wave_red64(ss2); sd = wave_red64(sd);

    float sc1 = 1.0f / fmaxf(sqrtf(ss1), 1e-12f);
    float sc2 = 1.0f / fmaxf(sqrtf(ss2), 1e-12f);
    float s18 = sc1 * 8.0f, s28 = sc2 * 8.0f;   // x8: keep fp8 values normal

    unsigned int* f1row = (unsigned int*)(feats + ((size_t)b * SEQ2 + s) * DIM);
    unsigned int* f2row = (unsigned int*)(feats + ((size_t)b * SEQ2 + SEQ + s) * DIM);
    #pragma unroll
    for (int it = 0; it < 4; it++) {
        int p1 = __builtin_amdgcn_cvt_pk_fp8_f32(av[it].x * s18, av[it].y * s18, 0, 0);
        p1     = __builtin_amdgcn_cvt_pk_fp8_f32(av[it].z * s18, av[it].w * s18, p1, 1);
        int p2 = __builtin_amdgcn_cvt_pk_fp8_f32(bv[it].x * s28, bv[it].y * s28, 0, 0);
        p2     = __builtin_amdgcn_cvt_pk_fp8_f32(bv[it].z * s28, bv[it].w * s28, p2, 1);
        f1row[lane + 64*it] = (unsigned int)p1;
        f2row[lane + 64*it] = (unsigned int)p2;
    }
    if (lane == 0) {
        pos_cos[tok] = sd * sc1 * sc2;
        Ng[2*tok] = 0.0f;
        Ng[2*tok + 1] = 0.0f;
        if (tok == 0) out[0] = 0.0f;   // loss blocks accumulate into out
    }
}

// ---------------------------------------------------------------------------
// Kernel 2: symmetric fused sim-GEMM + exp + neg-mask, MX-fp8 K=128.
// R9 structure: 64x64 tile, ONE WAVE per block -> ZERO barriers.  All
// ordering is wave-local:
//   iter k: 16x ds_read_b128 frags -> lgkmcnt(0) [reads done, buffer free]
//           -> stage(k+1) same buffer [16 DMA fly under MFMAs]
//           -> sched_barrier(0) -> 16 MFMA -> vmcnt(0) [tile k+1 landed]
// Stall-hiding comes from 9 INDEPENDENT waves/CU (LDS 16.9 KB/block), the
// pure m114 cross-wave overlap regime -- no convoy, no collective drain.
// LDS read amplification 2x -> 1x (wave reads only its own 16 KB/iter).
// Swizzle & fragment maps identical to R4 (row&7 == lane>>3 pattern holds).
// Cost: 2x L2 staging traffic (64-tiles halve reuse) -- L2 feed is the new
// floor; 2x Ng atomics (negligible).
// ---------------------------------------------------------------------------
__global__ __launch_bounds__(64, 2) void gemm_ng_kernel(
        const unsigned char* __restrict__ feats, const int* __restrict__ mask,
        float* __restrict__ Ng) {
    int bid = blockIdx.x;
    int b = bid & 7;                 // XCD-local batch (m09: placement %8); 9408%8==0
    int p = bid >> 3;                // 0..1175 triangular pair index
    int ti = 0;
    while (p >= TILES - ti) { p -= TILES - ti; ti++; }
    int tj = ti + p;
    int ibase = ti * BM, jbase = tj * BN;
    bool isdiag = (ti == tj);

    const unsigned char* fb = feats + (size_t)b * SEQ2 * DIM;

    __shared__ __align__(16) unsigned char As[BM][BK];  // 8 KB
    __shared__ __align__(16) unsigned char Bs[BN][BK];  // 8 KB
    __shared__ float mrow_s[BM];                        // 256 B
    __shared__ float mcol_s[BN];                        // 256 B

    int lane = threadIdx.x & 63;
    int colq = lane & 15, quad = lane >> 4;

    // Staging: per issue (1 KB = 8 rows x 128 B), lane covers row
    // q*8 + (lane>>3), slot lane&7 -> logical source chunk (lane&7)^(lane>>3).
    int sr = lane >> 3;
    int sc = (lane & 7) ^ sr;
    const unsigned char* a0 = fb + (size_t)(ibase + sr) * DIM + sc * 16;
    const unsigned char* b0 = fb + (size_t)(jbase + sr) * DIM + sc * 16;

    auto stage = [&](int it) {
        size_t kb = (size_t)it * BK;
        #pragma unroll
        for (int q = 0; q < 8; q++) {       // 8 rows per issue, 64 rows total
            async_ld16(a0 + (size_t)q * 8 * DIM + kb, (char*)&As[0][0] + q * 1024);
            async_ld16(b0 + (size_t)q * 8 * DIM + kb, (char*)&Bs[0][0] + q * 1024);
        }
    };

    stage(0);                            // DMA flies during mask setup

    // masks (as float) for the tile's rows/cols -- one lane each, wave-local
    {
        int i = ibase + lane; int im = (i < SEQ) ? i : i - SEQ;
        mrow_s[lane] = mask[b * SEQ + im] ? 1.0f : 0.0f;
        int j = jbase + lane; int jm = (j < SEQ) ? j : j - SEQ;
        mcol_s[lane] = mask[b * SEQ + jm] ? 1.0f : 0.0f;
    }
    asm volatile("s_waitcnt vmcnt(0)" ::: "memory");   // tile 0 resident

    f32x4 acc[4][4] = {};
    // swizzled byte offsets of the two 16B chunks holding k = quad*32..+31
    int s0 = ((2 * quad)     ^ (colq & 7)) * 16;
    int s1 = ((2 * quad + 1) ^ (colq & 7)) * 16;

    #pragma unroll 1
    for (int it = 0; it < KITERS; it++) {
        i32x8 af[4], bg[4];
        #pragma unroll
        for (int mi = 0; mi < 4; mi++) {
            int row = mi * 16 + colq;               // row&7 == colq&7
            i32x4 lo = *(const i32x4*)&As[row][s0];
            i32x4 hi = *(const i32x4*)&As[row][s1];
            af[mi] = __builtin_shufflevector(lo, hi, 0, 1, 2, 3, 4, 5, 6, 7);
        }
        #pragma unroll
        for (int nj = 0; nj < 4; nj++) {
            int row = nj * 16 + colq;
            i32x4 lo = *(const i32x4*)&Bs[row][s0];
            i32x4 hi = *(const i32x4*)&Bs[row][s1];
            bg[nj] = __builtin_shufflevector(lo, hi, 0, 1, 2, 3, 4, 5, 6, 7);
        }

        if (it + 1 < KITERS) {
            // wave-local: own reads done -> buffer safe for own DMA overwrite
            asm volatile("s_waitcnt lgkmcnt(0)" ::: "memory");
            __builtin_amdgcn_sched_barrier(0);
            stage(it + 1);                          // flies under the MFMAs
            __builtin_amdgcn_sched_barrier(0);      // MFMAs stay below issue
        }

        #pragma unroll
        for (int mi = 0; mi < 4; mi++)
            #pragma unroll
            for (int nj = 0; nj < 4; nj++)
                acc[mi][nj] = __builtin_amdgcn_mfma_scale_f32_16x16x128_f8f6f4(
                    af[mi], bg[nj], acc[mi][nj],
                    0, 0,                       // cbsz=fp8, blgp=fp8
                    0, 0x7F7F7F7F,              // opselA, scaleA = 2^0
                    0, 0x7F7F7F7F);             // opselB, scaleB = 2^0

        if (it + 1 < KITERS)
            asm volatile("s_waitcnt vmcnt(0)" ::: "memory");   // next tile landed
    }

    // Epilogue.  C/D layout: col = colq, row = quad*4 + reg.
    float mj[4]; int jglob[4];
    #pragma unroll
    for (int nj = 0; nj < 4; nj++) {
        int jl = nj * 16 + colq;
        mj[nj] = mcol_s[jl];
        jglob[nj] = jbase + jl;
    }
    float colsum[4] = {0.f, 0.f, 0.f, 0.f};

    #pragma unroll
    for (int mi = 0; mi < 4; mi++) {
        int il0 = mi * 16 + quad * 4;
        float rsum[4] = {0.f, 0.f, 0.f, 0.f};
        float mr[4];
        #pragma unroll
        for (int r = 0; r < 4; r++) mr[r] = mrow_s[il0 + r];
        #pragma unroll
        for (int nj = 0; nj < 4; nj++) {
            #pragma unroll
            for (int r = 0; r < 4; r++) {
                int d = (ibase + il0 + r) - jglob[nj];
                bool same = (d == 0) | (d == SEQ) | (d == -SEQ);
                float e = same ? 0.0f : __expf(acc[mi][nj][r] * EXP_SCALE);
                rsum[r] += e * mj[nj];
                colsum[nj] += e * mr[r];
            }
        }
        // reduce each row sum across the 16 column lanes
        #pragma unroll
        for (int r = 0; r < 4; r++) {
            float v = rsum[r];
            #pragma unroll
            for (int m = 1; m < 16; m <<= 1) v += __shfl_xor(v, m, 64);
            if (colq == 0)
                atomicAdd(&Ng[b * SEQ2 + ibase + il0 + r], v);
        }
    }

    if (!isdiag) {
        // reduce col sums across the 4 quads
        #pragma unroll
        for (int nj = 0; nj < 4; nj++) {
            float v = colsum[nj];
            v += __shfl_xor(v, 16, 64);
            v += __shfl_xor(v, 32, 64);
            if (quad == 0)
                atomicAdd(&Ng[b * SEQ2 + jglob[nj]], v);
        }
    }
}

// ---------------------------------------------------------------------------
// Kernel 3: per-batch masked mean of per-token loss, accumulated straight
// into out[0].  per_tok[i] = log1p(Ng[i] * exp(-pos_sim/T)).
// ---------------------------------------------------------------------------
__global__ __launch_bounds__(1024) void loss_kernel(
        const float* __restrict__ Ng, const float* __restrict__ pos_cos,
        const int* __restrict__ mask, float* __restrict__ out) {
    int b = blockIdx.x, t = threadIdx.x;
    float sum = 0.f, cnt = 0.f;
    for (int i = t; i < SEQ2; i += 1024) {
        int im = (i < SEQ) ? i : i - SEQ;
        if (mask[b * SEQ + im]) {
            float ps = pos_cos[b * SEQ + im] * TEMP_INV;
            float ng = Ng[b * SEQ2 + i];
            sum += log1pf(ng * __expf(-ps));
            cnt += 1.0f;
        }
    }
    sum = wave_red64(sum); cnt = wave_red64(cnt);
    __shared__ float rs[16], rc[16];
    int lane = t & 63, w = t >> 6;
    if (lane == 0) { rs[w] = sum; rc[w] = cnt; }
    __syncthreads();
    if (t == 0) {
        float s = 0.f, c = 0.f;
        #pragma unroll
        for (int k = 0; k < 16; k++) { s += rs[k]; c += rc[k]; }
        atomicAdd(out, s / c * (1.0f / BATCH));
    }
}

// ---------------------------------------------------------------------------
extern "C" void kernel_launch(void* const* d_in, const int* in_sizes, int n_in,
                              void* d_out, int out_size, void* d_ws, size_t ws_size,
                              hipStream_t stream) {
    const float* h1  = (const float*)d_in[0];
    const float* h2  = (const float*)d_in[1];
    const int* mask  = (const int*)d_in[2];
    float* out       = (float*)d_out;

    char* ws = (char*)d_ws;
    size_t feats_bytes = (size_t)BATCH * SEQ2 * DIM;          // 25,165,824 (fp8)
    unsigned char* feats = (unsigned char*)ws;
    float* pos_cos    = (float*)(ws + feats_bytes);
    float* Ng         = (float*)(ws + feats_bytes + (size_t)BATCH * SEQ * 4);

    normalize_kernel<<<BATCH * SEQ / 4, 256, 0, stream>>>(h1, h2, feats, pos_cos, Ng, out);

    gemm_ng_kernel<<<NPAIRS * BATCH, 64, 0, stream>>>(feats, mask, Ng);

    loss_kernel<<<BATCH, 1024, 0, stream>>>(Ng, pos_cos, mask, out);
}